// Round 2
// baseline (158.556 us; speedup 1.0000x reference)
//
#include <hip/hip_runtime.h>

#define NEMB 512
#define DIM 64
#define NB 32
#define HW 4096                 // 64*64 spatial per batch
#define NTOK (NB * HW)          // 131072 tokens
#define TPB 256
#define KCHUNK 256              // codes staged per LDS chunk
#define NCHUNK (NEMB / KCHUNK)  // 2
#define BLOCKS (NTOK / TPB)     // 512
#define BLK_PER_B (HW / TPB)    // 16

// One token per thread. z vector in registers; codebook broadcast from LDS.
// d2 = (sum(z^2) - 2*dot) + sum(c^2), sequential-FMA dot, strict-< argmin
// (== jnp.argmin first-index tie-break).
__global__ __launch_bounds__(TPB, 2)
void vq_main(const float* __restrict__ z_e, const float* __restrict__ cb,
             float* __restrict__ out, float* __restrict__ loss_part,
             float* __restrict__ inds_out)
{
    __shared__ float cb_s[KCHUNK][DIM];   // 64 KB
    __shared__ float sumc_s[KCHUNK];      // 1 KB
    __shared__ float red_s[TPB];          // 1 KB

    const int tid = threadIdx.x;
    const int gid = blockIdx.x;
    const int b   = gid / BLK_PER_B;
    const int hw  = (gid % BLK_PER_B) * TPB + tid;

    const float* zb = z_e + (size_t)b * DIM * HW;

    // Load token into registers; sumz with rounded squares then adds
    // (matches jnp.sum(flat*flat): no FMA contraction).
    float z[DIM];
    float sumz = 0.f;
    {
#pragma clang fp contract(off)
#pragma unroll
        for (int d = 0; d < DIM; ++d) {
            float v = zb[(size_t)d * HW + hw];   // coalesced across lanes
            z[d] = v;
            float p = v * v;
            sumz = sumz + p;
        }
    }

    float best  = 3.402823466e38f;
    int   bestk = 0;

    for (int c = 0; c < NCHUNK; ++c) {
        __syncthreads();  // protect cb_s reuse across chunks
        {   // stage 256 codes (64 KB) cooperatively, float4
            const float4* s4 = (const float4*)(cb + (size_t)c * KCHUNK * DIM);
            float4*       d4 = (float4*)(&cb_s[0][0]);
#pragma unroll
            for (int i = 0; i < (KCHUNK * DIM / 4) / TPB; ++i)
                d4[i * TPB + tid] = s4[i * TPB + tid];
        }
        __syncthreads();
        {   // sum(c^2) for code 'tid' of this chunk (rounded squares, then adds)
#pragma clang fp contract(off)
            float s = 0.f;
#pragma unroll
            for (int d = 0; d < DIM; ++d) {
                float v = cb_s[tid][d];
                float p = v * v;
                s = s + p;
            }
            sumc_s[tid] = s;
        }
        __syncthreads();

        // two codes per iteration: 2 independent FMA chains for ILP,
        // each dot strictly sequential over d (match GEMM k-order)
        for (int k = 0; k < KCHUNK; k += 2) {
            float acc0 = 0.f, acc1 = 0.f;
#pragma unroll
            for (int d = 0; d < DIM; ++d) {
                acc0 = fmaf(z[d], cb_s[k][d],     acc0);
                acc1 = fmaf(z[d], cb_s[k + 1][d], acc1);
            }
            float d2a = (sumz - 2.0f * acc0) + sumc_s[k];
            float d2b = (sumz - 2.0f * acc1) + sumc_s[k + 1];
            int   kk  = c * KCHUNK + k;
            if (d2a < best) { best = d2a; bestk = kk; }
            if (d2b < best) { best = d2b; bestk = kk + 1; }
        }
    }

    // ---- epilogue ----
    // index output (reference dtype int32 -> harness compares as float)
    inds_out[(size_t)gid * TPB + tid] = (float)bestk;

    // gather code row (float4, L2-cached), straight-through out, loss partial
    const float4* q4 = (const float4*)(cb + (size_t)bestk * DIM);
    float*        ob = out + (size_t)b * DIM * HW;
    float lsum = 0.f;
    {
#pragma clang fp contract(off)
#pragma unroll
        for (int g = 0; g < DIM / 4; ++g) {
            float4 q = q4[g];
            float qv[4] = {q.x, q.y, q.z, q.w};
#pragma unroll
            for (int j = 0; j < 4; ++j) {
                int d = g * 4 + j;
                float t1 = qv[j] - z[d];              // fl(z_q - z)
                ob[(size_t)d * HW + hw] = z[d] + t1;  // fl(z + fl(z_q - z))
                float p = t1 * t1;                    // (z - z_q)^2 (negation exact)
                lsum = lsum + p;
            }
        }
    }

    // deterministic block reduction of loss partials
    __syncthreads();
    red_s[tid] = lsum;
    __syncthreads();
#pragma unroll
    for (int s = TPB / 2; s > 0; s >>= 1) {
        if (tid < s) red_s[tid] = red_s[tid] + red_s[tid + s];
        __syncthreads();
    }
    if (tid == 0) loss_part[gid] = red_s[0];
}

// deterministic final reduce: 16 partials per batch, fixed order
__global__ void vq_loss_final(const float* __restrict__ part,
                              float* __restrict__ loss_out)
{
    int b = threadIdx.x;
    if (b < NB) {
        float s = 0.f;
        for (int i = 0; i < BLK_PER_B; ++i)
            s = s + part[b * BLK_PER_B + i];
        float m = s * (1.0f / (HW * DIM));   // exact /2^18
        loss_out[b] = m + 0.25f * m;         // mean(a) + 0.25*mean(b), a==b
    }
}

extern "C" void kernel_launch(void* const* d_in, const int* in_sizes, int n_in,
                              void* d_out, int out_size, void* d_ws, size_t ws_size,
                              hipStream_t stream)
{
    const float* z_e = (const float*)d_in[0];
    const float* cb  = (const float*)d_in[1];

    float* out  = (float*)d_out;
    float* loss = out + (size_t)NB * DIM * HW;  // offset 8388608
    float* inds = loss + NB;                    // offset 8388640
    float* part = (float*)d_ws;                 // 512 floats of scratch

    vq_main<<<BLOCKS, TPB, 0, stream>>>(z_e, cb, out, part, inds);
    vq_loss_final<<<1, 64, 0, stream>>>(part, loss);
}